// Round 10
// baseline (236.104 us; speedup 1.0000x reference)
//
#include <hip/hip_runtime.h>
#include <math.h>

#define N_NODES 100000
#define R_REL   1000
#define T_TRI   600000
#define D_DIM   128
#define OUT_STRIDE 640
#define NBUCK   65

typedef unsigned int  u32;
typedef unsigned short u16;

__device__ __forceinline__ float wave_sum(float v) {
    #pragma unroll
    for (int off = 32; off > 0; off >>= 1) v += __shfl_xor(v, off);
    return v;
}
__device__ __forceinline__ float half32_sum(float v) {
    v += __shfl_xor(v, 1); v += __shfl_xor(v, 2); v += __shfl_xor(v, 4);
    v += __shfl_xor(v, 8); v += __shfl_xor(v, 16);
    return v;
}
__device__ __forceinline__ float sub16_sum(float v) {
    v += __shfl_xor(v, 1); v += __shfl_xor(v, 2);
    v += __shfl_xor(v, 4); v += __shfl_xor(v, 8);
    return v;
}
__device__ __forceinline__ float fast_tanh(float x) {
    float e = __expf(2.f * x);
    return 1.f - __fdividef(2.f, e + 1.f);
}
__device__ __forceinline__ float4 tanh4(float4 v) {
    float4 o; o.x = fast_tanh(v.x); o.y = fast_tanh(v.y);
    o.z = fast_tanh(v.z); o.w = fast_tanh(v.w);
    return o;
}
__device__ __forceinline__ float dot4(float4 a, float4 b) {
    return a.x*b.x + a.y*b.y + a.z*b.z + a.w*b.w;
}
__device__ __forceinline__ u32 bfr(float x) {
    u32 u = __float_as_uint(x);
    return (u + 0x7fffu + ((u >> 16) & 1u)) >> 16;
}
__device__ __forceinline__ uint2 pack_bf4(float4 v) {
    uint2 p;
    p.x = bfr(v.x) | (bfr(v.y) << 16);
    p.y = bfr(v.z) | (bfr(v.w) << 16);
    return p;
}
__device__ __forceinline__ void unpack_bf8(uint4 v, float f[8]) {
    f[0] = __uint_as_float(v.x << 16); f[1] = __uint_as_float(v.x & 0xffff0000u);
    f[2] = __uint_as_float(v.y << 16); f[3] = __uint_as_float(v.y & 0xffff0000u);
    f[4] = __uint_as_float(v.z << 16); f[5] = __uint_as_float(v.z & 0xffff0000u);
    f[6] = __uint_as_float(v.w << 16); f[7] = __uint_as_float(v.w & 0xffff0000u);
}

// prep: tanh+pack, normalized-rel prep, rowptrs, degree histogram (LDS preagg)
__global__ void k_prep(const float* __restrict__ feat, const float* __restrict__ rel,
                       const float* __restrict__ attk,
                       float* __restrict__ out, u16* __restrict__ bf0,
                       u16* __restrict__ relu_bf, float* __restrict__ wtab,
                       const int* __restrict__ adj_rows, const int* __restrict__ hn_rows,
                       int* __restrict__ rpa, int* __restrict__ rph,
                       u32* __restrict__ hist) {
    __shared__ u32 lhist[2 * NBUCK];
    int tid = threadIdx.x;
    for (int i = tid; i < 2 * NBUCK; i += blockDim.x) lhist[i] = 0;
    __syncthreads();
    int gt = blockIdx.x * blockDim.x + tid;
    int gstride = gridDim.x * blockDim.x;

    for (int i = gt; i < N_NODES * D_DIM / 4; i += gstride) {
        int n = i >> 5, d4 = i & 31;
        float4 v = ((const float4*)feat)[i];
        float4 t = tanh4(v);
        ((float4*)(out + (size_t)n * OUT_STRIDE))[d4] = t;
        ((uint2*)(bf0 + (size_t)n * D_DIM))[d4] = pack_bf4(t);
    }
    int gw = gt >> 6, lane = tid & 63;
    int nwaves = gstride >> 6;
    for (int r = gw; r < R_REL; r += nwaves) {
        float2 a  = ((const float2*)rel)[r * 64 + lane];
        float2 k0 = ((const float2*)attk)[lane];
        float2 k1 = ((const float2*)(attk + D_DIM))[lane];
        float nrm2 = wave_sum(a.x * a.x + a.y * a.y);
        float d0 = wave_sum(a.x * k0.x + a.y * k0.y);
        float d1 = wave_sum(a.x * k1.x + a.y * k1.y);
        float inv = __frsqrt_rn(nrm2);
        ((u32*)relu_bf)[r * 64 + lane] = bfr(a.x * inv) | (bfr(a.y * inv) << 16);
        if (lane == 0) {
            wtab[r]         = __expf(d0 * inv);
            wtab[R_REL + r] = __expf(d1 * inv);
        }
    }
    for (int i = gt; i < 2 * (N_NODES + 1); i += gstride) {
        const int* rows; int* p; int n;
        if (i <= N_NODES) { rows = adj_rows; p = rpa; n = i; }
        else { rows = hn_rows; p = rph; n = i - (N_NODES + 1); }
        int lo = 0, hi = T_TRI;
        while (lo < hi) { int m = (lo + hi) >> 1; if (rows[m] < n) lo = m + 1; else hi = m; }
        p[n] = lo;
    }
    for (int i = gt; i < 2 * N_NODES; i += gstride) {
        const int* rows = (i < N_NODES) ? adj_rows : hn_rows;
        int n = (i < N_NODES) ? i : i - N_NODES;
        int lo = 0, hi = T_TRI;
        while (lo < hi) { int m = (lo + hi) >> 1; if (rows[m] < n) lo = m + 1; else hi = m; }
        int lo2 = lo, hi2 = T_TRI;
        while (lo2 < hi2) { int m = (lo2 + hi2) >> 1; if (rows[m] < n + 1) lo2 = m + 1; else hi2 = m; }
        int b = min(lo2 - lo, 64);
        atomicAdd(&lhist[((i < N_NODES) ? 0 : NBUCK) + b], 1u);
    }
    __syncthreads();
    for (int i = tid; i < 2 * NBUCK; i += blockDim.x)
        if (lhist[i]) atomicAdd(&hist[i], lhist[i]);
}

__global__ void k_scan(const u32* __restrict__ hist, u32* __restrict__ goff) {
    if (threadIdx.x == 0 && blockIdx.x == 0) {
        u32 s = 0;
        for (int b = 0; b < NBUCK; ++b) { goff[b] = s; s += hist[b]; }
        s = 0;
        for (int b = 0; b < NBUCK; ++b) { goff[NBUCK + b] = s; s += hist[NBUCK + b]; }
    }
}

// two-phase scatter: block-local counts -> reserve global ranges -> place
__global__ void k_scatter(const int* __restrict__ rpa, const int* __restrict__ rph,
                          u32* __restrict__ goff,
                          int* __restrict__ perm_adj, int* __restrict__ perm_high) {
    __shared__ u32 lcnt[2 * NBUCK];
    __shared__ u32 lbase[2 * NBUCK];
    __shared__ u32 lpos[2 * NBUCK];
    int tid = threadIdx.x;
    for (int i = tid; i < 2 * NBUCK; i += blockDim.x) { lcnt[i] = 0; lpos[i] = 0; }
    __syncthreads();
    int gt = blockIdx.x * blockDim.x + tid;
    int b = -1, n = -1;
    if (gt < 2 * N_NODES) {
        const int* rp = (gt < N_NODES) ? rpa : rph;
        n = (gt < N_NODES) ? gt : gt - N_NODES;
        int deg = rp[n + 1] - rp[n];
        b = min(deg, 64) + ((gt < N_NODES) ? 0 : NBUCK);
        atomicAdd(&lcnt[b], 1u);
    }
    __syncthreads();
    for (int i = tid; i < 2 * NBUCK; i += blockDim.x)
        if (lcnt[i]) lbase[i] = atomicAdd(&goff[i], lcnt[i]);
    __syncthreads();
    if (b >= 0) {
        u32 pos = lbase[b] + atomicAdd(&lpos[b], 1u);
        if (b < NBUCK) perm_adj[pos] = n; else perm_high[pos] = n;
    }
}

// 2 rows/wave (degree-matched via perm), 2 subgroups x 16 lanes per row, 8 dims/lane.
// Normalized rel (u): reflected = n - (2*w*(n.u))*u ; z(rv==0) edges encoded by sign.
__global__ __launch_bounds__(256) void k_nr_layer(
    float* __restrict__ outbuf, int out_off,
    const u16* __restrict__ in_bf,
    u16* __restrict__ out_bf,
    const int* __restrict__ row_ptr,
    const int* __restrict__ col,
    const int* __restrict__ ridx1,
    const float* __restrict__ r_val,
    const u16* __restrict__ relu_bf,
    const float* __restrict__ wtab,
    const int* __restrict__ perm,
    const float* __restrict__ ha,
    float* __restrict__ eproj_out) {
    __shared__ float s_w[4][64];
    int wslot = threadIdx.x >> 6;
    int lane  = threadIdx.x & 63;
    int wid2  = (blockIdx.x * blockDim.x + threadIdx.x) >> 6;
    int idx2  = wid2 * 2 + (lane >> 5);
    if (idx2 >= N_NODES) return;
    int row = perm[idx2];
    int ll  = lane & 31;
    int sgl = (lane >> 4) & 1;
    int sl  = lane & 15;
    int beg = row_ptr[row], end = row_ptr[row + 1];
    int deg = end - beg;
    float* orow = outbuf + (size_t)row * OUT_STRIDE + out_off;

    if (deg == 0) {
        float4 z = {0.f,0.f,0.f,0.f};
        ((float4*)orow)[ll] = z;
        if (out_bf != nullptr && ll < 16) {
            uint4 zz = {0u,0u,0u,0u};
            ((uint4*)(out_bf + (size_t)row * D_DIM))[ll] = zz;
        }
        if (ha != nullptr && ll == 0) eproj_out[row] = 1.f;
        return;
    }

    // pass A: lane ll owns edge beg+ll (deg<=32 fast path)
    int  t0 = beg + ll;
    bool va = t0 < end;
    int  ta = va ? t0 : beg;
    int  rt_a = ridx1[ta];
    float rv_a = r_val[ta];
    bool  z_a  = (rv_a == 0.f);
    float w_a  = va ? (z_a ? 1.f : wtab[rt_a]) : 0.f;

    // pre-issue iter0 + iter1 gathers
    int  tb0 = beg + sgl, tb1 = beg + 2 + sgl;
    bool v0 = tb0 < end, v1 = tb1 < end;
    int  tc0 = v0 ? tb0 : beg, tc1 = v1 ? tb1 : beg;
    int  cc0 = col[tc0],   cc1 = col[tc1];
    int  rr0 = ridx1[tc0], rr1 = ridx1[tc1];
    uint4 F0 = ((const uint4*)(in_bf   + (size_t)cc0 * D_DIM))[sl];
    uint4 U0 = ((const uint4*)(relu_bf + (size_t)rr0 * D_DIM))[sl];
    uint4 F1 = ((const uint4*)(in_bf   + (size_t)cc1 * D_DIM))[sl];
    uint4 U1 = ((const uint4*)(relu_bf + (size_t)rr1 * D_DIM))[sl];

    // row sum over 32-lane half
    float lsum = w_a;
    for (int t = t0 + 32; t < end; t += 32) {
        int rt = ridx1[t]; float rv = r_val[t];
        lsum += (rv == 0.f) ? 1.f : wtab[rt];
    }
    float inv_s = 1.f / half32_sum(lsum);
    float sw = w_a * inv_s;
    s_w[wslot][lane] = z_a ? -sw : sw;
    int hb = lane & 32;

    // iter 0
    float sv = s_w[wslot][hb + sgl];
    float w0 = fabsf(sv);
    float nf[8], uf[8];
    unpack_bf8(F0, nf); unpack_bf8(U0, uf);
    float pd = 0.f;
    #pragma unroll
    for (int j = 0; j < 8; ++j) pd += nf[j] * uf[j];
    pd = sub16_sum(pd);
    float b0 = (sv < 0.f) ? 0.f : 2.f * w0 * pd;
    float acc[8];
    #pragma unroll
    for (int j = 0; j < 8; ++j) acc[j] = w0 * nf[j] - b0 * uf[j];

    // steady state
    int niter = (deg + 1) >> 1;
    int cur_tc = tc1, cur_rr = rr1; bool cur_v = v1;
    for (int it = 1; it < niter; ++it) {
        int tb = beg + 2 * (it + 1) + sgl;
        bool nv = tb < end;
        int  ntc = nv ? tb : beg;
        int  ncc = col[ntc];
        int  nrr = ridx1[ntc];
        uint4 NF = ((const uint4*)(in_bf   + (size_t)ncc * D_DIM))[sl];
        uint4 NU = ((const uint4*)(relu_bf + (size_t)nrr * D_DIM))[sl];

        int idx = 2 * it + sgl;
        float sv2;
        if (idx < 32) sv2 = s_w[wslot][hb + idx];     // 0 for idx>=deg by construction
        else {
            float rv = r_val[cur_tc];
            bool z = (rv == 0.f);
            float wv = cur_v ? (z ? 1.f : wtab[cur_rr]) * inv_s : 0.f;
            sv2 = z ? -wv : wv;
        }
        float w = fabsf(sv2);
        float gf[8], qf[8];
        unpack_bf8(F1, gf); unpack_bf8(U1, qf);
        float pdt = 0.f;
        #pragma unroll
        for (int j = 0; j < 8; ++j) pdt += gf[j] * qf[j];
        pdt = sub16_sum(pdt);
        float bt = (sv2 < 0.f) ? 0.f : 2.f * w * pdt;
        #pragma unroll
        for (int j = 0; j < 8; ++j) acc[j] += w * gf[j] - bt * qf[j];

        F1 = NF; U1 = NU;
        cur_tc = ntc; cur_rr = nrr; cur_v = nv;
    }

    // combine row's 2 subgroup partials
    #pragma unroll
    for (int j = 0; j < 8; ++j) acc[j] += __shfl_xor(acc[j], 16);

    float4 q = (sgl == 0) ? make_float4(acc[0], acc[1], acc[2], acc[3])
                          : make_float4(acc[4], acc[5], acc[6], acc[7]);
    float4 tq = tanh4(q);
    ((float4*)orow)[2 * sl + sgl] = tq;
    if (out_bf != nullptr)
        ((uint2*)(out_bf + (size_t)row * D_DIM))[2 * sl + sgl] = pack_bf4(tq);
    if (ha != nullptr) {
        const float4* ha4 = (const float4*)ha;
        float pdp = dot4(tq, ha4[2 * sl + sgl]);
        pdp = sub16_sum(pdp);
        pdp += __shfl_xor(pdp, 16);
        if (ll == 0) eproj_out[row] = __expf(pdp);
    }
}

__global__ __launch_bounds__(256) void k_high_layer(
    float* __restrict__ outbuf, int out_off,
    const u16* __restrict__ in_bf,
    u16* __restrict__ out_bf,
    const int* __restrict__ row_ptr,
    const int* __restrict__ hcol,
    const float* __restrict__ eproj,
    const int* __restrict__ perm,
    const float* __restrict__ ha,
    float* __restrict__ eproj_out) {
    __shared__ float s_w[4][64];
    int wslot = threadIdx.x >> 6;
    int lane  = threadIdx.x & 63;
    int wid2  = (blockIdx.x * blockDim.x + threadIdx.x) >> 6;
    int idx2  = wid2 * 2 + (lane >> 5);
    if (idx2 >= N_NODES) return;
    int row = perm[idx2];
    int ll  = lane & 31;
    int sgl = (lane >> 4) & 1;
    int sl  = lane & 15;
    int beg = row_ptr[row], end = row_ptr[row + 1];
    int deg = end - beg;
    float* orow = outbuf + (size_t)row * OUT_STRIDE + out_off;

    if (deg == 0) {
        float4 z = {0.f,0.f,0.f,0.f};
        ((float4*)orow)[ll] = z;
        if (out_bf != nullptr && ll < 16) {
            uint4 zz = {0u,0u,0u,0u};
            ((uint4*)(out_bf + (size_t)row * D_DIM))[ll] = zz;
        }
        if (ha != nullptr && ll == 0) eproj_out[row] = 1.f;
        return;
    }

    int  t0 = beg + ll;
    bool va = t0 < end;
    int  ta = va ? t0 : beg;
    int  c_a = hcol[ta];
    float e_a = eproj[c_a];
    e_a = va ? e_a : 0.f;

    int  tb0 = beg + sgl, tb1 = beg + 2 + sgl;
    bool v0 = tb0 < end, v1 = tb1 < end;
    int  tc0 = v0 ? tb0 : beg, tc1 = v1 ? tb1 : beg;
    int  cc0 = hcol[tc0], cc1 = hcol[tc1];
    uint4 F0 = ((const uint4*)(in_bf + (size_t)cc0 * D_DIM))[sl];
    uint4 F1 = ((const uint4*)(in_bf + (size_t)cc1 * D_DIM))[sl];

    float lsum = e_a;
    for (int t = t0 + 32; t < end; t += 32)
        lsum += eproj[hcol[t]];
    float inv_s = 1.f / half32_sum(lsum);
    s_w[wslot][lane] = e_a * inv_s;
    int hb = lane & 32;

    float w0 = s_w[wslot][hb + sgl];          // 0 for invalid edges by construction
    float nf[8];
    unpack_bf8(F0, nf);
    float acc[8];
    #pragma unroll
    for (int j = 0; j < 8; ++j) acc[j] = w0 * nf[j];

    int niter = (deg + 1) >> 1;
    int cur_cc = cc1; bool cur_v = v1;
    for (int it = 1; it < niter; ++it) {
        int tb = beg + 2 * (it + 1) + sgl;
        bool nv = tb < end;
        int  ntc = nv ? tb : beg;
        int  ncc = hcol[ntc];
        uint4 NF = ((const uint4*)(in_bf + (size_t)ncc * D_DIM))[sl];

        int idx = 2 * it + sgl;
        float w;
        if (idx < 32) w = s_w[wslot][hb + idx];
        else          w = cur_v ? eproj[cur_cc] * inv_s : 0.f;
        float gf[8];
        unpack_bf8(F1, gf);
        #pragma unroll
        for (int j = 0; j < 8; ++j) acc[j] += w * gf[j];

        F1 = NF; cur_cc = ncc; cur_v = nv;
    }

    #pragma unroll
    for (int j = 0; j < 8; ++j) acc[j] += __shfl_xor(acc[j], 16);

    float4 q = (sgl == 0) ? make_float4(acc[0], acc[1], acc[2], acc[3])
                          : make_float4(acc[4], acc[5], acc[6], acc[7]);
    float4 tq = tanh4(q);
    ((float4*)orow)[2 * sl + sgl] = tq;
    if (out_bf != nullptr)
        ((uint2*)(out_bf + (size_t)row * D_DIM))[2 * sl + sgl] = pack_bf4(tq);
    if (ha != nullptr) {
        const float4* ha4 = (const float4*)ha;
        float pdp = dot4(tq, ha4[2 * sl + sgl]);
        pdp = sub16_sum(pdp);
        pdp += __shfl_xor(pdp, 16);
        if (ll == 0) eproj_out[row] = __expf(pdp);
    }
}

extern "C" void kernel_launch(void* const* d_in, const int* in_sizes, int n_in,
                              void* d_out, int out_size, void* d_ws, size_t ws_size,
                              hipStream_t stream) {
    const float* features  = (const float*)d_in[0];
    const float* rel_emb   = (const float*)d_in[1];
    const float* r_val     = (const float*)d_in[2];
    const float* attk      = (const float*)d_in[3];
    const float* high_atts = (const float*)d_in[4];
    const int*   adj       = (const int*)d_in[5];
    const int*   r_index   = (const int*)d_in[6];
    const int*   high_nei  = (const int*)d_in[7];
    float* out = (float*)d_out;

    char* ws = (char*)d_ws;
    auto take = [&](size_t bytes) -> char* {
        char* p = ws;
        ws += (bytes + 255) & ~(size_t)255;
        return p;
    };
    u32*   hist         = (u32*)take(2 * NBUCK * sizeof(u32));   // zeroed below
    u32*   goff         = (u32*)take(2 * NBUCK * sizeof(u32));
    int*   row_ptr_adj  = (int*)take((N_NODES + 1) * sizeof(int));
    int*   row_ptr_high = (int*)take((N_NODES + 1) * sizeof(int));
    int*   perm_adj     = (int*)take(N_NODES * sizeof(int));
    int*   perm_high    = (int*)take(N_NODES * sizeof(int));
    float* wtab         = (float*)take(2 * R_REL * sizeof(float));
    float* eproj0       = (float*)take(N_NODES * sizeof(float));
    float* eproj1       = (float*)take(N_NODES * sizeof(float));
    u16*   relu_bf      = (u16*)take((size_t)R_REL * D_DIM * sizeof(u16));
    u16*   fbf0         = (u16*)take((size_t)N_NODES * D_DIM * sizeof(u16));
    u16*   fbf1         = (u16*)take((size_t)N_NODES * D_DIM * sizeof(u16));
    u16*   fbf2         = (u16*)take((size_t)N_NODES * D_DIM * sizeof(u16));
    u16*   fbf3         = (u16*)take((size_t)N_NODES * D_DIM * sizeof(u16));

    hipMemsetAsync(hist, 0, 2 * 256 + 2 * NBUCK * sizeof(u32), stream); // hist (+pad into goff region is overwritten by scan)

    k_prep<<<4096, 256, 0, stream>>>(features, rel_emb, attk, out, fbf0,
                                     relu_bf, wtab, adj, high_nei,
                                     row_ptr_adj, row_ptr_high, hist);
    k_scan<<<1, 64, 0, stream>>>(hist, goff);
    k_scatter<<<(2 * N_NODES + 255) / 256, 256, 0, stream>>>(
        row_ptr_adj, row_ptr_high, goff, perm_adj, perm_high);

    int pair_blocks = ((N_NODES + 1) / 2 + 3) / 4;

    k_nr_layer<<<pair_blocks, 256, 0, stream>>>(
        out, 1 * D_DIM, fbf0, fbf1,
        row_ptr_adj, adj + T_TRI, r_index + T_TRI, r_val,
        relu_bf, wtab + 0 * R_REL, perm_adj, nullptr, nullptr);
    k_nr_layer<<<pair_blocks, 256, 0, stream>>>(
        out, 2 * D_DIM, fbf1, fbf2,
        row_ptr_adj, adj + T_TRI, r_index + T_TRI, r_val,
        relu_bf, wtab + 1 * R_REL, perm_adj, high_atts + 0 * D_DIM, eproj0);
    k_high_layer<<<pair_blocks, 256, 0, stream>>>(
        out, 3 * D_DIM, fbf2, fbf3,
        row_ptr_high, high_nei + T_TRI, eproj0, perm_high,
        high_atts + 1 * D_DIM, eproj1);
    k_high_layer<<<pair_blocks, 256, 0, stream>>>(
        out, 4 * D_DIM, fbf3, nullptr,
        row_ptr_high, high_nei + T_TRI, eproj1, perm_high,
        nullptr, nullptr);
}

// Round 11
// 211.006 us; speedup vs baseline: 1.1189x; 1.1189x over previous
//
#include <hip/hip_runtime.h>
#include <math.h>

#define N_NODES 100000
#define R_REL   1000
#define T_TRI   600000
#define D_DIM   128
#define OUT_STRIDE 640

typedef unsigned int  u32;
typedef unsigned short u16;

__device__ __forceinline__ float wave_sum(float v) {
    #pragma unroll
    for (int off = 32; off > 0; off >>= 1) v += __shfl_xor(v, off);
    return v;
}
__device__ __forceinline__ float half32_sum(float v) {
    v += __shfl_xor(v, 1); v += __shfl_xor(v, 2); v += __shfl_xor(v, 4);
    v += __shfl_xor(v, 8); v += __shfl_xor(v, 16);
    return v;
}
__device__ __forceinline__ float sub16_sum(float v) {
    v += __shfl_xor(v, 1); v += __shfl_xor(v, 2);
    v += __shfl_xor(v, 4); v += __shfl_xor(v, 8);
    return v;
}
__device__ __forceinline__ float fast_tanh(float x) {
    float e = __expf(2.f * x);
    return 1.f - __fdividef(2.f, e + 1.f);
}
__device__ __forceinline__ float4 tanh4(float4 v) {
    float4 o; o.x = fast_tanh(v.x); o.y = fast_tanh(v.y);
    o.z = fast_tanh(v.z); o.w = fast_tanh(v.w);
    return o;
}
__device__ __forceinline__ float dot4(float4 a, float4 b) {
    return a.x*b.x + a.y*b.y + a.z*b.z + a.w*b.w;
}
__device__ __forceinline__ u32 bfr(float x) {
    u32 u = __float_as_uint(x);
    return (u + 0x7fffu + ((u >> 16) & 1u)) >> 16;
}
__device__ __forceinline__ uint2 pack_bf4(float4 v) {
    uint2 p;
    p.x = bfr(v.x) | (bfr(v.y) << 16);
    p.y = bfr(v.z) | (bfr(v.w) << 16);
    return p;
}
__device__ __forceinline__ void unpack_bf8(uint4 v, float f[8]) {
    f[0] = __uint_as_float(v.x << 16); f[1] = __uint_as_float(v.x & 0xffff0000u);
    f[2] = __uint_as_float(v.y << 16); f[3] = __uint_as_float(v.y & 0xffff0000u);
    f[4] = __uint_as_float(v.z << 16); f[5] = __uint_as_float(v.z & 0xffff0000u);
    f[6] = __uint_as_float(v.w << 16); f[7] = __uint_as_float(v.w & 0xffff0000u);
}

// prep: tanh+pack chunk0, normalized-rel prep, both rowptrs — one launch
__global__ void k_prep(const float* __restrict__ feat, const float* __restrict__ rel,
                       const float* __restrict__ attk,
                       float* __restrict__ out, u16* __restrict__ bf0,
                       u16* __restrict__ relu_bf, float* __restrict__ wtab,
                       const int* __restrict__ adj_rows, const int* __restrict__ hn_rows,
                       int* __restrict__ rpa, int* __restrict__ rph) {
    int tid = threadIdx.x;
    int gt = blockIdx.x * blockDim.x + tid;
    int gstride = gridDim.x * blockDim.x;

    for (int i = gt; i < N_NODES * D_DIM / 4; i += gstride) {
        int n = i >> 5, d4 = i & 31;
        float4 v = ((const float4*)feat)[i];
        float4 t = tanh4(v);
        ((float4*)(out + (size_t)n * OUT_STRIDE))[d4] = t;
        ((uint2*)(bf0 + (size_t)n * D_DIM))[d4] = pack_bf4(t);
    }
    int gw = gt >> 6, lane = tid & 63;
    int nwaves = gstride >> 6;
    for (int r = gw; r < R_REL; r += nwaves) {
        float2 a  = ((const float2*)rel)[r * 64 + lane];
        float2 k0 = ((const float2*)attk)[lane];
        float2 k1 = ((const float2*)(attk + D_DIM))[lane];
        float nrm2 = wave_sum(a.x * a.x + a.y * a.y);
        float d0 = wave_sum(a.x * k0.x + a.y * k0.y);
        float d1 = wave_sum(a.x * k1.x + a.y * k1.y);
        float inv = __frsqrt_rn(nrm2);
        ((u32*)relu_bf)[r * 64 + lane] = bfr(a.x * inv) | (bfr(a.y * inv) << 16);
        if (lane == 0) {
            wtab[r]         = __expf(d0 * inv);
            wtab[R_REL + r] = __expf(d1 * inv);
        }
    }
    for (int i = gt; i < 2 * (N_NODES + 1); i += gstride) {
        const int* rows; int* p; int n;
        if (i <= N_NODES) { rows = adj_rows; p = rpa; n = i; }
        else { rows = hn_rows; p = rph; n = i - (N_NODES + 1); }
        int lo = 0, hi = T_TRI;
        while (lo < hi) { int m = (lo + hi) >> 1; if (rows[m] < n) lo = m + 1; else hi = m; }
        p[n] = lo;
    }
}

// 2 rows/wave (adjacent rows: contiguous edge ranges + adjacent output rows),
// 2 subgroups x 16 lanes per row, 8 dims/lane.  Normalized rel u:
// reflected = n - (2*w*(n.u))*u ; z(rv==0) edges encoded via weight sign.
__global__ __launch_bounds__(256) void k_nr_layer(
    float* __restrict__ outbuf, int out_off,
    const u16* __restrict__ in_bf,
    u16* __restrict__ out_bf,
    const int* __restrict__ row_ptr,
    const int* __restrict__ col,
    const int* __restrict__ ridx1,
    const float* __restrict__ r_val,
    const u16* __restrict__ relu_bf,
    const float* __restrict__ wtab,
    const float* __restrict__ ha,
    float* __restrict__ eproj_out) {
    __shared__ float s_w[4][64];
    int wslot = threadIdx.x >> 6;
    int lane  = threadIdx.x & 63;
    int wid2  = (blockIdx.x * blockDim.x + threadIdx.x) >> 6;
    int row   = wid2 * 2 + (lane >> 5);
    if (row >= N_NODES) return;
    int ll  = lane & 31;
    int sgl = (lane >> 4) & 1;
    int sl  = lane & 15;
    int beg = row_ptr[row], end = row_ptr[row + 1];
    int deg = end - beg;
    float* orow = outbuf + (size_t)row * OUT_STRIDE + out_off;

    if (deg == 0) {
        float4 z = {0.f,0.f,0.f,0.f};
        ((float4*)orow)[ll] = z;
        if (out_bf != nullptr && ll < 16) {
            uint4 zz = {0u,0u,0u,0u};
            ((uint4*)(out_bf + (size_t)row * D_DIM))[ll] = zz;
        }
        if (ha != nullptr && ll == 0) eproj_out[row] = 1.f;
        return;
    }

    // pass A: lane ll owns edge beg+ll (deg<=32 fast path)
    int  t0 = beg + ll;
    bool va = t0 < end;
    int  ta = va ? t0 : beg;
    int  rt_a = ridx1[ta];
    float rv_a = r_val[ta];
    bool  z_a  = (rv_a == 0.f);
    float w_a  = va ? (z_a ? 1.f : wtab[rt_a]) : 0.f;

    // pre-issue iter0 + iter1 gathers
    int  tb0 = beg + sgl, tb1 = beg + 2 + sgl;
    bool v0 = tb0 < end, v1 = tb1 < end;
    int  tc0 = v0 ? tb0 : beg, tc1 = v1 ? tb1 : beg;
    int  cc0 = col[tc0],   cc1 = col[tc1];
    int  rr0 = ridx1[tc0], rr1 = ridx1[tc1];
    uint4 F0 = ((const uint4*)(in_bf   + (size_t)cc0 * D_DIM))[sl];
    uint4 U0 = ((const uint4*)(relu_bf + (size_t)rr0 * D_DIM))[sl];
    uint4 F1 = ((const uint4*)(in_bf   + (size_t)cc1 * D_DIM))[sl];
    uint4 U1 = ((const uint4*)(relu_bf + (size_t)rr1 * D_DIM))[sl];

    // row sum over 32-lane half
    float lsum = w_a;
    for (int t = t0 + 32; t < end; t += 32) {
        int rt = ridx1[t]; float rv = r_val[t];
        lsum += (rv == 0.f) ? 1.f : wtab[rt];
    }
    float inv_s = 1.f / half32_sum(lsum);
    float sw = w_a * inv_s;
    s_w[wslot][lane] = z_a ? -sw : sw;
    int hb = lane & 32;

    // iter 0
    float sv = s_w[wslot][hb + sgl];
    float w0 = fabsf(sv);
    float nf[8], uf[8];
    unpack_bf8(F0, nf); unpack_bf8(U0, uf);
    float pd = 0.f;
    #pragma unroll
    for (int j = 0; j < 8; ++j) pd += nf[j] * uf[j];
    pd = sub16_sum(pd);
    float b0 = (sv < 0.f) ? 0.f : 2.f * w0 * pd;
    float acc[8];
    #pragma unroll
    for (int j = 0; j < 8; ++j) acc[j] = w0 * nf[j] - b0 * uf[j];

    // steady state (2-deep pipelined; halves may diverge, no cross-half ops)
    int niter = (deg + 1) >> 1;
    int cur_tc = tc1, cur_rr = rr1; bool cur_v = v1;
    for (int it = 1; it < niter; ++it) {
        int tb = beg + 2 * (it + 1) + sgl;
        bool nv = tb < end;
        int  ntc = nv ? tb : beg;
        int  ncc = col[ntc];
        int  nrr = ridx1[ntc];
        uint4 NF = ((const uint4*)(in_bf   + (size_t)ncc * D_DIM))[sl];
        uint4 NU = ((const uint4*)(relu_bf + (size_t)nrr * D_DIM))[sl];

        int idx = 2 * it + sgl;
        float sv2;
        if (idx < 32) sv2 = s_w[wslot][hb + idx];     // 0 beyond deg by construction
        else {
            float rv = r_val[cur_tc];
            bool z = (rv == 0.f);
            float wv = cur_v ? (z ? 1.f : wtab[cur_rr]) * inv_s : 0.f;
            sv2 = z ? -wv : wv;
        }
        float w = fabsf(sv2);
        float gf[8], qf[8];
        unpack_bf8(F1, gf); unpack_bf8(U1, qf);
        float pdt = 0.f;
        #pragma unroll
        for (int j = 0; j < 8; ++j) pdt += gf[j] * qf[j];
        pdt = sub16_sum(pdt);
        float bt = (sv2 < 0.f) ? 0.f : 2.f * w * pdt;
        #pragma unroll
        for (int j = 0; j < 8; ++j) acc[j] += w * gf[j] - bt * qf[j];

        F1 = NF; U1 = NU;
        cur_tc = ntc; cur_rr = nrr; cur_v = nv;
    }

    // combine row's 2 subgroup partials
    #pragma unroll
    for (int j = 0; j < 8; ++j) acc[j] += __shfl_xor(acc[j], 16);

    float4 q = (sgl == 0) ? make_float4(acc[0], acc[1], acc[2], acc[3])
                          : make_float4(acc[4], acc[5], acc[6], acc[7]);
    float4 tq = tanh4(q);
    ((float4*)orow)[2 * sl + sgl] = tq;
    if (out_bf != nullptr)
        ((uint2*)(out_bf + (size_t)row * D_DIM))[2 * sl + sgl] = pack_bf4(tq);
    if (ha != nullptr) {
        const float4* ha4 = (const float4*)ha;
        float pdp = dot4(tq, ha4[2 * sl + sgl]);
        pdp = sub16_sum(pdp);
        pdp += __shfl_xor(pdp, 16);
        if (ll == 0) eproj_out[row] = __expf(pdp);
    }
}

__global__ __launch_bounds__(256) void k_high_layer(
    float* __restrict__ outbuf, int out_off,
    const u16* __restrict__ in_bf,
    u16* __restrict__ out_bf,
    const int* __restrict__ row_ptr,
    const int* __restrict__ hcol,
    const float* __restrict__ eproj,
    const float* __restrict__ ha,
    float* __restrict__ eproj_out) {
    __shared__ float s_w[4][64];
    int wslot = threadIdx.x >> 6;
    int lane  = threadIdx.x & 63;
    int wid2  = (blockIdx.x * blockDim.x + threadIdx.x) >> 6;
    int row   = wid2 * 2 + (lane >> 5);
    if (row >= N_NODES) return;
    int ll  = lane & 31;
    int sgl = (lane >> 4) & 1;
    int sl  = lane & 15;
    int beg = row_ptr[row], end = row_ptr[row + 1];
    int deg = end - beg;
    float* orow = outbuf + (size_t)row * OUT_STRIDE + out_off;

    if (deg == 0) {
        float4 z = {0.f,0.f,0.f,0.f};
        ((float4*)orow)[ll] = z;
        if (out_bf != nullptr && ll < 16) {
            uint4 zz = {0u,0u,0u,0u};
            ((uint4*)(out_bf + (size_t)row * D_DIM))[ll] = zz;
        }
        if (ha != nullptr && ll == 0) eproj_out[row] = 1.f;
        return;
    }

    int  t0 = beg + ll;
    bool va = t0 < end;
    int  ta = va ? t0 : beg;
    int  c_a = hcol[ta];
    float e_a = eproj[c_a];
    e_a = va ? e_a : 0.f;

    int  tb0 = beg + sgl, tb1 = beg + 2 + sgl;
    bool v0 = tb0 < end, v1 = tb1 < end;
    int  tc0 = v0 ? tb0 : beg, tc1 = v1 ? tb1 : beg;
    int  cc0 = hcol[tc0], cc1 = hcol[tc1];
    uint4 F0 = ((const uint4*)(in_bf + (size_t)cc0 * D_DIM))[sl];
    uint4 F1 = ((const uint4*)(in_bf + (size_t)cc1 * D_DIM))[sl];

    float lsum = e_a;
    for (int t = t0 + 32; t < end; t += 32)
        lsum += eproj[hcol[t]];
    float inv_s = 1.f / half32_sum(lsum);
    s_w[wslot][lane] = e_a * inv_s;
    int hb = lane & 32;

    float w0 = s_w[wslot][hb + sgl];
    float nf[8];
    unpack_bf8(F0, nf);
    float acc[8];
    #pragma unroll
    for (int j = 0; j < 8; ++j) acc[j] = w0 * nf[j];

    int niter = (deg + 1) >> 1;
    int cur_cc = cc1; bool cur_v = v1;
    for (int it = 1; it < niter; ++it) {
        int tb = beg + 2 * (it + 1) + sgl;
        bool nv = tb < end;
        int  ntc = nv ? tb : beg;
        int  ncc = hcol[ntc];
        uint4 NF = ((const uint4*)(in_bf + (size_t)ncc * D_DIM))[sl];

        int idx = 2 * it + sgl;
        float w;
        if (idx < 32) w = s_w[wslot][hb + idx];
        else          w = cur_v ? eproj[cur_cc] * inv_s : 0.f;
        float gf[8];
        unpack_bf8(F1, gf);
        #pragma unroll
        for (int j = 0; j < 8; ++j) acc[j] += w * gf[j];

        F1 = NF; cur_cc = ncc; cur_v = nv;
    }

    #pragma unroll
    for (int j = 0; j < 8; ++j) acc[j] += __shfl_xor(acc[j], 16);

    float4 q = (sgl == 0) ? make_float4(acc[0], acc[1], acc[2], acc[3])
                          : make_float4(acc[4], acc[5], acc[6], acc[7]);
    float4 tq = tanh4(q);
    ((float4*)orow)[2 * sl + sgl] = tq;
    if (out_bf != nullptr)
        ((uint2*)(out_bf + (size_t)row * D_DIM))[2 * sl + sgl] = pack_bf4(tq);
    if (ha != nullptr) {
        const float4* ha4 = (const float4*)ha;
        float pdp = dot4(tq, ha4[2 * sl + sgl]);
        pdp = sub16_sum(pdp);
        pdp += __shfl_xor(pdp, 16);
        if (ll == 0) eproj_out[row] = __expf(pdp);
    }
}

extern "C" void kernel_launch(void* const* d_in, const int* in_sizes, int n_in,
                              void* d_out, int out_size, void* d_ws, size_t ws_size,
                              hipStream_t stream) {
    const float* features  = (const float*)d_in[0];
    const float* rel_emb   = (const float*)d_in[1];
    const float* r_val     = (const float*)d_in[2];
    const float* attk      = (const float*)d_in[3];
    const float* high_atts = (const float*)d_in[4];
    const int*   adj       = (const int*)d_in[5];
    const int*   r_index   = (const int*)d_in[6];
    const int*   high_nei  = (const int*)d_in[7];
    float* out = (float*)d_out;

    char* ws = (char*)d_ws;
    auto take = [&](size_t bytes) -> char* {
        char* p = ws;
        ws += (bytes + 255) & ~(size_t)255;
        return p;
    };
    int*   row_ptr_adj  = (int*)take((N_NODES + 1) * sizeof(int));
    int*   row_ptr_high = (int*)take((N_NODES + 1) * sizeof(int));
    float* wtab         = (float*)take(2 * R_REL * sizeof(float));
    float* eproj0       = (float*)take(N_NODES * sizeof(float));
    float* eproj1       = (float*)take(N_NODES * sizeof(float));
    u16*   relu_bf      = (u16*)take((size_t)R_REL * D_DIM * sizeof(u16));
    u16*   fbf0         = (u16*)take((size_t)N_NODES * D_DIM * sizeof(u16));
    u16*   fbf1         = (u16*)take((size_t)N_NODES * D_DIM * sizeof(u16));
    u16*   fbf2         = (u16*)take((size_t)N_NODES * D_DIM * sizeof(u16));
    u16*   fbf3         = (u16*)take((size_t)N_NODES * D_DIM * sizeof(u16));

    k_prep<<<4096, 256, 0, stream>>>(features, rel_emb, attk, out, fbf0,
                                     relu_bf, wtab, adj, high_nei,
                                     row_ptr_adj, row_ptr_high);

    int pair_blocks = ((N_NODES + 1) / 2 + 3) / 4;   // 2 rows/wave, 4 waves/block

    k_nr_layer<<<pair_blocks, 256, 0, stream>>>(
        out, 1 * D_DIM, fbf0, fbf1,
        row_ptr_adj, adj + T_TRI, r_index + T_TRI, r_val,
        relu_bf, wtab + 0 * R_REL, nullptr, nullptr);
    k_nr_layer<<<pair_blocks, 256, 0, stream>>>(
        out, 2 * D_DIM, fbf1, fbf2,
        row_ptr_adj, adj + T_TRI, r_index + T_TRI, r_val,
        relu_bf, wtab + 1 * R_REL, high_atts + 0 * D_DIM, eproj0);
    k_high_layer<<<pair_blocks, 256, 0, stream>>>(
        out, 3 * D_DIM, fbf2, fbf3,
        row_ptr_high, high_nei + T_TRI, eproj0, high_atts + 1 * D_DIM, eproj1);
    k_high_layer<<<pair_blocks, 256, 0, stream>>>(
        out, 4 * D_DIM, fbf3, nullptr,
        row_ptr_high, high_nei + T_TRI, eproj1, nullptr, nullptr);
}

// Round 12
// 209.046 us; speedup vs baseline: 1.1294x; 1.0094x over previous
//
#include <hip/hip_runtime.h>
#include <math.h>

#define N_NODES 100000
#define R_REL   1000
#define T_TRI   600000
#define D_DIM   128
#define OUT_STRIDE 640

typedef unsigned int  u32;
typedef unsigned short u16;

// ---- DPP 16-lane all-reduce (VALU pipe, no DS) ----
template<int CTRL>
__device__ __forceinline__ float dpp_add(float x) {
    int xi = __float_as_int(x);
    int r = __builtin_amdgcn_update_dpp(xi, xi, CTRL, 0xf, 0xf, false);
    return x + __int_as_float(r);
}
__device__ __forceinline__ float row16_sum(float v) {
    v = dpp_add<0x121>(v);   // row_ror:1
    v = dpp_add<0x122>(v);   // row_ror:2
    v = dpp_add<0x124>(v);   // row_ror:4
    v = dpp_add<0x128>(v);   // row_ror:8
    return v;
}
__device__ __forceinline__ float wave_sum(float v) {
    #pragma unroll
    for (int off = 32; off > 0; off >>= 1) v += __shfl_xor(v, off);
    return v;
}
__device__ __forceinline__ float half32_sum(float v) {   // 32-lane half all-reduce
    v = row16_sum(v);
    v += __shfl_xor(v, 16);
    return v;
}
__device__ __forceinline__ float fast_tanh(float x) {
    float e = __expf(2.f * x);
    return 1.f - __fdividef(2.f, e + 1.f);
}
__device__ __forceinline__ float4 tanh4(float4 v) {
    float4 o; o.x = fast_tanh(v.x); o.y = fast_tanh(v.y);
    o.z = fast_tanh(v.z); o.w = fast_tanh(v.w);
    return o;
}
__device__ __forceinline__ float dot4(float4 a, float4 b) {
    return a.x*b.x + a.y*b.y + a.z*b.z + a.w*b.w;
}
__device__ __forceinline__ u32 bfr(float x) {
    u32 u = __float_as_uint(x);
    return (u + 0x7fffu + ((u >> 16) & 1u)) >> 16;
}
__device__ __forceinline__ uint2 pack_bf4(float4 v) {
    uint2 p;
    p.x = bfr(v.x) | (bfr(v.y) << 16);
    p.y = bfr(v.z) | (bfr(v.w) << 16);
    return p;
}
__device__ __forceinline__ void unpack_bf8(uint4 v, float f[8]) {
    f[0] = __uint_as_float(v.x << 16); f[1] = __uint_as_float(v.x & 0xffff0000u);
    f[2] = __uint_as_float(v.y << 16); f[3] = __uint_as_float(v.y & 0xffff0000u);
    f[4] = __uint_as_float(v.z << 16); f[5] = __uint_as_float(v.z & 0xffff0000u);
    f[6] = __uint_as_float(v.w << 16); f[7] = __uint_as_float(v.w & 0xffff0000u);
}

// prep: tanh+pack chunk0, normalized-rel prep, both rowptrs — one launch
__global__ void k_prep(const float* __restrict__ feat, const float* __restrict__ rel,
                       const float* __restrict__ attk,
                       float* __restrict__ out, u16* __restrict__ bf0,
                       u16* __restrict__ relu_bf, float* __restrict__ wtab,
                       const int* __restrict__ adj_rows, const int* __restrict__ hn_rows,
                       int* __restrict__ rpa, int* __restrict__ rph) {
    int tid = threadIdx.x;
    int gt = blockIdx.x * blockDim.x + tid;
    int gstride = gridDim.x * blockDim.x;

    for (int i = gt; i < N_NODES * D_DIM / 4; i += gstride) {
        int n = i >> 5, d4 = i & 31;
        float4 v = ((const float4*)feat)[i];
        float4 t = tanh4(v);
        ((float4*)(out + (size_t)n * OUT_STRIDE))[d4] = t;
        ((uint2*)(bf0 + (size_t)n * D_DIM))[d4] = pack_bf4(t);
    }
    int gw = gt >> 6, lane = tid & 63;
    int nwaves = gstride >> 6;
    for (int r = gw; r < R_REL; r += nwaves) {
        float2 a  = ((const float2*)rel)[r * 64 + lane];
        float2 k0 = ((const float2*)attk)[lane];
        float2 k1 = ((const float2*)(attk + D_DIM))[lane];
        float nrm2 = wave_sum(a.x * a.x + a.y * a.y);
        float d0 = wave_sum(a.x * k0.x + a.y * k0.y);
        float d1 = wave_sum(a.x * k1.x + a.y * k1.y);
        float inv = __frsqrt_rn(nrm2);
        ((u32*)relu_bf)[r * 64 + lane] = bfr(a.x * inv) | (bfr(a.y * inv) << 16);
        if (lane == 0) {
            wtab[r]         = __expf(d0 * inv);
            wtab[R_REL + r] = __expf(d1 * inv);
        }
    }
    for (int i = gt; i < 2 * (N_NODES + 1); i += gstride) {
        const int* rows; int* p; int n;
        if (i <= N_NODES) { rows = adj_rows; p = rpa; n = i; }
        else { rows = hn_rows; p = rph; n = i - (N_NODES + 1); }
        int lo = 0, hi = T_TRI;
        while (lo < hi) { int m = (lo + hi) >> 1; if (rows[m] < n) lo = m + 1; else hi = m; }
        p[n] = lo;
    }
}

// 2 rows/wave, 2 subgroups x 16 lanes per row, 8 dims/lane.  Normalized rel u:
// reflected = n - (2*w*(n.u))*u ; z(rv==0) edges encoded via weight sign.
// Per-edge dot reduce is DPP (VALU pipe); cross-row combines stay on DS.
__global__ __launch_bounds__(256) void k_nr_layer(
    float* __restrict__ outbuf, int out_off,
    const u16* __restrict__ in_bf,
    u16* __restrict__ out_bf,
    const int* __restrict__ row_ptr,
    const int* __restrict__ col,
    const int* __restrict__ ridx1,
    const float* __restrict__ r_val,
    const u16* __restrict__ relu_bf,
    const float* __restrict__ wtab,
    const float* __restrict__ ha,
    float* __restrict__ eproj_out) {
    __shared__ float s_w[4][64];
    int wslot = threadIdx.x >> 6;
    int lane  = threadIdx.x & 63;
    int wid2  = (blockIdx.x * blockDim.x + threadIdx.x) >> 6;
    int row   = wid2 * 2 + (lane >> 5);
    if (row >= N_NODES) return;
    int ll  = lane & 31;
    int sgl = (lane >> 4) & 1;
    int sl  = lane & 15;
    int beg = row_ptr[row], end = row_ptr[row + 1];
    int deg = end - beg;
    float* orow = outbuf + (size_t)row * OUT_STRIDE + out_off;

    if (deg == 0) {
        float4 z = {0.f,0.f,0.f,0.f};
        ((float4*)orow)[ll] = z;
        if (out_bf != nullptr && ll < 16) {
            uint4 zz = {0u,0u,0u,0u};
            ((uint4*)(out_bf + (size_t)row * D_DIM))[ll] = zz;
        }
        if (ha != nullptr && ll == 0) eproj_out[row] = 1.f;
        return;
    }

    // pass A: lane ll owns edge beg+ll (deg<=32 fast path)
    int  t0 = beg + ll;
    bool va = t0 < end;
    int  ta = va ? t0 : beg;
    int  rt_a = ridx1[ta];
    float rv_a = r_val[ta];
    bool  z_a  = (rv_a == 0.f);
    float w_a  = va ? (z_a ? 1.f : wtab[rt_a]) : 0.f;

    // pre-issue iter0 + iter1 gathers
    int  tb0 = beg + sgl, tb1 = beg + 2 + sgl;
    bool v0 = tb0 < end, v1 = tb1 < end;
    int  tc0 = v0 ? tb0 : beg, tc1 = v1 ? tb1 : beg;
    int  cc0 = col[tc0],   cc1 = col[tc1];
    int  rr0 = ridx1[tc0], rr1 = ridx1[tc1];
    uint4 F0 = ((const uint4*)(in_bf   + (size_t)cc0 * D_DIM))[sl];
    uint4 U0 = ((const uint4*)(relu_bf + (size_t)rr0 * D_DIM))[sl];
    uint4 F1 = ((const uint4*)(in_bf   + (size_t)cc1 * D_DIM))[sl];
    uint4 U1 = ((const uint4*)(relu_bf + (size_t)rr1 * D_DIM))[sl];

    // row sum over 32-lane half (DPP + one xor16)
    float lsum = w_a;
    for (int t = t0 + 32; t < end; t += 32) {
        int rt = ridx1[t]; float rv = r_val[t];
        lsum += (rv == 0.f) ? 1.f : wtab[rt];
    }
    float inv_s = 1.f / half32_sum(lsum);
    float sw = w_a * inv_s;
    s_w[wslot][lane] = z_a ? -sw : sw;
    int hb = lane & 32;

    // iter 0
    float sv = s_w[wslot][hb + sgl];
    float w0 = fabsf(sv);
    float nf[8], uf[8];
    unpack_bf8(F0, nf); unpack_bf8(U0, uf);
    float pd = 0.f;
    #pragma unroll
    for (int j = 0; j < 8; ++j) pd += nf[j] * uf[j];
    pd = row16_sum(pd);
    float b0 = (sv < 0.f) ? 0.f : 2.f * w0 * pd;
    float acc[8];
    #pragma unroll
    for (int j = 0; j < 8; ++j) acc[j] = w0 * nf[j] - b0 * uf[j];

    // steady state (2-deep pipelined; halves may diverge, no cross-half ops)
    int niter = (deg + 1) >> 1;
    int cur_tc = tc1, cur_rr = rr1; bool cur_v = v1;
    for (int it = 1; it < niter; ++it) {
        int tb = beg + 2 * (it + 1) + sgl;
        bool nv = tb < end;
        int  ntc = nv ? tb : beg;
        int  ncc = col[ntc];
        int  nrr = ridx1[ntc];
        uint4 NF = ((const uint4*)(in_bf   + (size_t)ncc * D_DIM))[sl];
        uint4 NU = ((const uint4*)(relu_bf + (size_t)nrr * D_DIM))[sl];

        int idx = 2 * it + sgl;
        float sv2;
        if (idx < 32) sv2 = s_w[wslot][hb + idx];     // 0 beyond deg by construction
        else {
            float rv = r_val[cur_tc];
            bool z = (rv == 0.f);
            float wv = cur_v ? (z ? 1.f : wtab[cur_rr]) * inv_s : 0.f;
            sv2 = z ? -wv : wv;
        }
        float w = fabsf(sv2);
        float gf[8], qf[8];
        unpack_bf8(F1, gf); unpack_bf8(U1, qf);
        float pdt = 0.f;
        #pragma unroll
        for (int j = 0; j < 8; ++j) pdt += gf[j] * qf[j];
        pdt = row16_sum(pdt);
        float bt = (sv2 < 0.f) ? 0.f : 2.f * w * pdt;
        #pragma unroll
        for (int j = 0; j < 8; ++j) acc[j] += w * gf[j] - bt * qf[j];

        F1 = NF; U1 = NU;
        cur_tc = ntc; cur_rr = nrr; cur_v = nv;
    }

    // combine row's 2 subgroup partials
    #pragma unroll
    for (int j = 0; j < 8; ++j) acc[j] += __shfl_xor(acc[j], 16);

    float4 q = (sgl == 0) ? make_float4(acc[0], acc[1], acc[2], acc[3])
                          : make_float4(acc[4], acc[5], acc[6], acc[7]);
    float4 tq = tanh4(q);
    ((float4*)orow)[2 * sl + sgl] = tq;
    if (out_bf != nullptr)
        ((uint2*)(out_bf + (size_t)row * D_DIM))[2 * sl + sgl] = pack_bf4(tq);
    if (ha != nullptr) {
        const float4* ha4 = (const float4*)ha;
        float pdp = dot4(tq, ha4[2 * sl + sgl]);
        pdp = row16_sum(pdp);
        pdp += __shfl_xor(pdp, 16);
        if (ll == 0) eproj_out[row] = __expf(pdp);
    }
}

__global__ __launch_bounds__(256) void k_high_layer(
    float* __restrict__ outbuf, int out_off,
    const u16* __restrict__ in_bf,
    u16* __restrict__ out_bf,
    const int* __restrict__ row_ptr,
    const int* __restrict__ hcol,
    const float* __restrict__ eproj,
    const float* __restrict__ ha,
    float* __restrict__ eproj_out) {
    __shared__ float s_w[4][64];
    int wslot = threadIdx.x >> 6;
    int lane  = threadIdx.x & 63;
    int wid2  = (blockIdx.x * blockDim.x + threadIdx.x) >> 6;
    int row   = wid2 * 2 + (lane >> 5);
    if (row >= N_NODES) return;
    int ll  = lane & 31;
    int sgl = (lane >> 4) & 1;
    int sl  = lane & 15;
    int beg = row_ptr[row], end = row_ptr[row + 1];
    int deg = end - beg;
    float* orow = outbuf + (size_t)row * OUT_STRIDE + out_off;

    if (deg == 0) {
        float4 z = {0.f,0.f,0.f,0.f};
        ((float4*)orow)[ll] = z;
        if (out_bf != nullptr && ll < 16) {
            uint4 zz = {0u,0u,0u,0u};
            ((uint4*)(out_bf + (size_t)row * D_DIM))[ll] = zz;
        }
        if (ha != nullptr && ll == 0) eproj_out[row] = 1.f;
        return;
    }

    int  t0 = beg + ll;
    bool va = t0 < end;
    int  ta = va ? t0 : beg;
    int  c_a = hcol[ta];
    float e_a = eproj[c_a];
    e_a = va ? e_a : 0.f;

    int  tb0 = beg + sgl, tb1 = beg + 2 + sgl;
    bool v0 = tb0 < end, v1 = tb1 < end;
    int  tc0 = v0 ? tb0 : beg, tc1 = v1 ? tb1 : beg;
    int  cc0 = hcol[tc0], cc1 = hcol[tc1];
    uint4 F0 = ((const uint4*)(in_bf + (size_t)cc0 * D_DIM))[sl];
    uint4 F1 = ((const uint4*)(in_bf + (size_t)cc1 * D_DIM))[sl];

    float lsum = e_a;
    for (int t = t0 + 32; t < end; t += 32)
        lsum += eproj[hcol[t]];
    float inv_s = 1.f / half32_sum(lsum);
    s_w[wslot][lane] = e_a * inv_s;
    int hb = lane & 32;

    float w0 = s_w[wslot][hb + sgl];
    float nf[8];
    unpack_bf8(F0, nf);
    float acc[8];
    #pragma unroll
    for (int j = 0; j < 8; ++j) acc[j] = w0 * nf[j];

    int niter = (deg + 1) >> 1;
    int cur_cc = cc1; bool cur_v = v1;
    for (int it = 1; it < niter; ++it) {
        int tb = beg + 2 * (it + 1) + sgl;
        bool nv = tb < end;
        int  ntc = nv ? tb : beg;
        int  ncc = hcol[ntc];
        uint4 NF = ((const uint4*)(in_bf + (size_t)ncc * D_DIM))[sl];

        int idx = 2 * it + sgl;
        float w;
        if (idx < 32) w = s_w[wslot][hb + idx];
        else          w = cur_v ? eproj[cur_cc] * inv_s : 0.f;
        float gf[8];
        unpack_bf8(F1, gf);
        #pragma unroll
        for (int j = 0; j < 8; ++j) acc[j] += w * gf[j];

        F1 = NF; cur_cc = ncc; cur_v = nv;
    }

    #pragma unroll
    for (int j = 0; j < 8; ++j) acc[j] += __shfl_xor(acc[j], 16);

    float4 q = (sgl == 0) ? make_float4(acc[0], acc[1], acc[2], acc[3])
                          : make_float4(acc[4], acc[5], acc[6], acc[7]);
    float4 tq = tanh4(q);
    ((float4*)orow)[2 * sl + sgl] = tq;
    if (out_bf != nullptr)
        ((uint2*)(out_bf + (size_t)row * D_DIM))[2 * sl + sgl] = pack_bf4(tq);
    if (ha != nullptr) {
        const float4* ha4 = (const float4*)ha;
        float pdp = dot4(tq, ha4[2 * sl + sgl]);
        pdp = row16_sum(pdp);
        pdp += __shfl_xor(pdp, 16);
        if (ll == 0) eproj_out[row] = __expf(pdp);
    }
}

extern "C" void kernel_launch(void* const* d_in, const int* in_sizes, int n_in,
                              void* d_out, int out_size, void* d_ws, size_t ws_size,
                              hipStream_t stream) {
    const float* features  = (const float*)d_in[0];
    const float* rel_emb   = (const float*)d_in[1];
    const float* r_val     = (const float*)d_in[2];
    const float* attk      = (const float*)d_in[3];
    const float* high_atts = (const float*)d_in[4];
    const int*   adj       = (const int*)d_in[5];
    const int*   r_index   = (const int*)d_in[6];
    const int*   high_nei  = (const int*)d_in[7];
    float* out = (float*)d_out;

    char* ws = (char*)d_ws;
    auto take = [&](size_t bytes) -> char* {
        char* p = ws;
        ws += (bytes + 255) & ~(size_t)255;
        return p;
    };
    int*   row_ptr_adj  = (int*)take((N_NODES + 1) * sizeof(int));
    int*   row_ptr_high = (int*)take((N_NODES + 1) * sizeof(int));
    float* wtab         = (float*)take(2 * R_REL * sizeof(float));
    float* eproj0       = (float*)take(N_NODES * sizeof(float));
    float* eproj1       = (float*)take(N_NODES * sizeof(float));
    u16*   relu_bf      = (u16*)take((size_t)R_REL * D_DIM * sizeof(u16));
    u16*   fbf0         = (u16*)take((size_t)N_NODES * D_DIM * sizeof(u16));
    u16*   fbf1         = (u16*)take((size_t)N_NODES * D_DIM * sizeof(u16));
    u16*   fbf2         = (u16*)take((size_t)N_NODES * D_DIM * sizeof(u16));
    u16*   fbf3         = (u16*)take((size_t)N_NODES * D_DIM * sizeof(u16));

    k_prep<<<4096, 256, 0, stream>>>(features, rel_emb, attk, out, fbf0,
                                     relu_bf, wtab, adj, high_nei,
                                     row_ptr_adj, row_ptr_high);

    int pair_blocks = ((N_NODES + 1) / 2 + 3) / 4;   // 2 rows/wave, 4 waves/block

    k_nr_layer<<<pair_blocks, 256, 0, stream>>>(
        out, 1 * D_DIM, fbf0, fbf1,
        row_ptr_adj, adj + T_TRI, r_index + T_TRI, r_val,
        relu_bf, wtab + 0 * R_REL, nullptr, nullptr);
    k_nr_layer<<<pair_blocks, 256, 0, stream>>>(
        out, 2 * D_DIM, fbf1, fbf2,
        row_ptr_adj, adj + T_TRI, r_index + T_TRI, r_val,
        relu_bf, wtab + 1 * R_REL, high_atts + 0 * D_DIM, eproj0);
    k_high_layer<<<pair_blocks, 256, 0, stream>>>(
        out, 3 * D_DIM, fbf2, fbf3,
        row_ptr_high, high_nei + T_TRI, eproj0, high_atts + 1 * D_DIM, eproj1);
    k_high_layer<<<pair_blocks, 256, 0, stream>>>(
        out, 4 * D_DIM, fbf3, nullptr,
        row_ptr_high, high_nei + T_TRI, eproj1, nullptr, nullptr);
}